// Round 18
// baseline (327.333 us; speedup 1.0000x reference)
//
#include <hip/hip_runtime.h>

// Guided filter, Round 17 (resubmit — GPUAcquisitionTimeout, never measured):
// r6 block-phase structure + 4-tile software pipeline.
// r13 post-mortem: scanline spill-fixed (VGPR 44, WRITE back to 131MB) but
// 130us >= 121us kill-rule -> arc falsified (serial shfl chain). Revert to r6.
// r6 residual: all pipes <=57%, stage-1 serial load->LDS on every tile's
// critical path. Fix (T14): block owns 4 x-tiles; tile t+1 loads ISSUE at top
// of S2(t) (hidden under VALU), COMMIT to double-buffered sIP during S3(t).
// S2 (198thr x 3 ab-rows) and S3 (256thr x 2 rows) are r6 verbatim.
// LDS 2x10880+9504=31264B -> 5 blocks/CU. 2 barriers/tile unchanged.

constexpr int W  = 512, H = 512;
constexpr int TW = 64,  TH = 16, NT = 4;
constexpr int IPH = TH + 4;   // 20
constexpr int IPW = TW + 4;   // 68
constexpr int ABH = TH + 2;   // 18
constexpr int ABW = TW + 2;   // 66
constexpr float EPS  = 0.01f;
constexpr float INV9 = 1.0f / 9.0f;

template<bool INT>
__device__ __forceinline__ void stage2(
    const float2 (*sIPb)[IPW], float2 (*sAB)[ABW], int x0, int y0, int tid)
{
    if (tid < 198) {
        const int s   = tid / 33;
        const int p   = tid - 33 * s;
        const int ay0 = 3 * s;
        float hI[2][3], hP[2][3], hII[2][3], hIP[2][3];
        #pragma unroll
        for (int j = 0; j < 5; ++j) {
            const int rr = ay0 + j;
            const float4 c01 = *(const float4*)&sIPb[rr][2 * p];
            const float4 c23 = *(const float4*)&sIPb[rr][2 * p + 2];
            const float i0 = c01.x, q0 = c01.y, i1 = c01.z, q1 = c01.w;
            const float i2 = c23.x, q2 = c23.y, i3 = c23.z, q3 = c23.w;
            const int k = j % 3;
            const float tI  = i1 + i2, tP = q1 + q2;
            const float tII = fmaf(i1, i1, i2 * i2);
            const float tIP = fmaf(i1, q1, i2 * q2);
            hI[0][k]  = tI + i0;            hI[1][k]  = tI + i3;
            hP[0][k]  = tP + q0;            hP[1][k]  = tP + q3;
            hII[0][k] = fmaf(i0, i0, tII);  hII[1][k] = fmaf(i3, i3, tII);
            hIP[0][k] = fmaf(i0, q0, tIP);  hIP[1][k] = fmaf(i3, q3, tIP);
            if (j >= 2) {
                const int ay = ay0 + j - 2;
                float ab[4];
                #pragma unroll
                for (int c = 0; c < 2; ++c) {
                    const float wI  = hI[c][0]  + hI[c][1]  + hI[c][2];
                    const float wP  = hP[c][0]  + hP[c][1]  + hP[c][2];
                    const float wII = hII[c][0] + hII[c][1] + hII[c][2];
                    const float wIP = hIP[c][0] + hIP[c][1] + hIP[c][2];
                    float a = 0.f, b = 0.f;
                    if (INT) {
                        const float mI   = wI * INV9, mP = wP * INV9;
                        const float varI = fmaf(-mI, mI, wII * INV9);
                        const float cov  = fmaf(-mI, mP, wIP * INV9);
                        a = cov * __builtin_amdgcn_rcpf(varI + EPS);
                        b = fmaf(-a, mI, mP);
                    } else {
                        const int axg = x0 - 1 + 2 * p + c;
                        const int ayg = y0 - 1 + ay;
                        if ((unsigned)axg < (unsigned)W && (unsigned)ayg < (unsigned)H) {
                            const float cx = 3.f - (float)(axg == 0) - (float)(axg == W - 1);
                            const float cy = 3.f - (float)(ayg == 0) - (float)(ayg == H - 1);
                            const float inv  = __builtin_amdgcn_rcpf(cx * cy);
                            const float mI   = wI * inv, mP = wP * inv;
                            const float varI = fmaf(-mI, mI, wII * inv);
                            const float cov  = fmaf(-mI, mP, wIP * inv);
                            a = cov * __builtin_amdgcn_rcpf(varI + EPS);
                            b = fmaf(-a, mI, mP);
                        }
                    }
                    ab[2 * c] = a; ab[2 * c + 1] = b;
                }
                *(float4*)&sAB[ay][2 * p] = make_float4(ab[0], ab[1], ab[2], ab[3]);
            }
        }
    }
}

template<bool INT>
__device__ __forceinline__ void stage3(
    const float2 (*sAB)[ABW], const float* __restrict__ Ibase,
    float* __restrict__ Obase, int x0, int y0, int tid)
{
    const int q   = tid & 31;
    const int r   = tid >> 5;
    const int ox0 = 2 * q;
    const int oy0 = 2 * r;
    float hA[2][3], hB[2][3];
    #pragma unroll
    for (int j = 0; j < 4; ++j) {
        const float4 c01 = *(const float4*)&sAB[oy0 + j][ox0];
        const float4 c23 = *(const float4*)&sAB[oy0 + j][ox0 + 2];
        const float a0 = c01.x, b0 = c01.y, a1 = c01.z, b1 = c01.w;
        const float a2 = c23.x, b2 = c23.y, a3 = c23.z, b3 = c23.w;
        const int k = j % 3;
        const float tA = a1 + a2, tB = b1 + b2;
        hA[0][k] = tA + a0; hA[1][k] = tA + a3;
        hB[0][k] = tB + b0; hB[1][k] = tB + b3;
        if (j >= 2) {
            const int oy = oy0 + j - 2;
            const int gy = y0 + oy;
            const int go = gy * W + x0 + ox0;
            const float2 iv = *(const float2*)(Ibase + go);
            float res[2];
            #pragma unroll
            for (int c = 0; c < 2; ++c) {
                const float sa = hA[c][0] + hA[c][1] + hA[c][2];
                const float sb = hB[c][0] + hB[c][1] + hB[c][2];
                float inv;
                if (INT) {
                    inv = INV9;
                } else {
                    const int gxo = x0 + ox0 + c;
                    const float cx = 3.f - (float)(gxo == 0) - (float)(gxo == W - 1);
                    const float cy = 3.f - (float)(gy == 0) - (float)(gy == H - 1);
                    inv = __builtin_amdgcn_rcpf(cx * cy);
                }
                const float Ic = (c == 0) ? iv.x : iv.y;
                res[c] = fmaf(sa * inv, Ic, sb * inv);
            }
            *(float2*)(Obase + go) = make_float2(res[0], res[1]);
        }
    }
}

__global__ __launch_bounds__(256, 4) void guide_filter_kernel(
    const float* __restrict__ I, const float* __restrict__ P,
    float* __restrict__ O)
{
    __shared__ __align__(16) float2 sIP[2][IPH][IPW];
    __shared__ __align__(16) float2 sAB[ABH][ABW];

    const int tid   = threadIdx.x;
    const int y0    = blockIdx.y * TH;
    const int xbase = blockIdx.x * (NT * TW);
    const size_t img_off = (size_t)blockIdx.z * (size_t)(W * H);
    const float* Ib = I + img_off;
    const float* Pb = P + img_off;
    float*       Ob = O + img_off;

    // Per-thread staging task coords: 680 tasks in 3 rounds of 256.
    int trow[3], tpc[3]; bool tval[3];
    #pragma unroll
    for (int k = 0; k < 3; ++k) {
        const int task = tid + 256 * k;
        tval[k] = task < 34 * IPH;
        const int row = task / 34;
        trow[k] = row;
        tpc[k]  = task - 34 * row;
    }

    float2 rI[3], rP[3];
    // Issue: unconditional clamped loads (hoistable, no guards on the load).
    auto issue = [&](int x0n) {
        #pragma unroll
        for (int k = 0; k < 3; ++k) {
            int gy = y0 - 2 + trow[k];
            gy = gy < 0 ? 0 : (gy > H - 1 ? H - 1 : gy);
            int gx = x0n - 2 + 2 * tpc[k];
            gx = gx < 0 ? 0 : (gx > W - 2 ? W - 2 : gx);
            const size_t off = (size_t)gy * W + gx;
            rI[k] = *(const float2*)(Ib + off);
            rP[k] = *(const float2*)(Pb + off);
        }
    };
    // Commit: mask values for edge tiles (block-uniform branch), interleave, b128.
    auto commit = [&](float2 (*dst)[IPW], int x0n, bool intr) {
        #pragma unroll
        for (int k = 0; k < 3; ++k) {
            if (!tval[k]) continue;
            float i0 = rI[k].x, i1 = rI[k].y, q0 = rP[k].x, q1 = rP[k].y;
            if (!intr) {
                const int gy = y0 - 2 + trow[k];
                const int gx = x0n - 2 + 2 * tpc[k];
                const bool ry   = (unsigned)gy < (unsigned)H;
                const bool c0ok = ry & ((unsigned)gx < (unsigned)W);
                const bool c1ok = ry & ((unsigned)(gx + 1) < (unsigned)W);
                i0 = c0ok ? i0 : 0.f;  q0 = c0ok ? q0 : 0.f;
                i1 = c1ok ? i1 : 0.f;  q1 = c1ok ? q1 : 0.f;
            }
            *(float4*)&dst[trow[k]][2 * tpc[k]] = make_float4(i0, q0, i1, q1);
        }
    };

    // Prologue: stage tile 0 (exposed once per block of 4 tiles).
    {
        const int  x00   = xbase;
        const bool intr0 = (x00 > 0) & (x00 < W - TW) & (y0 > 0) & (y0 < H - TH);
        issue(x00);
        commit(sIP[0], x00, intr0);
    }

    int buf = 0;
    for (int t = 0; t < NT; ++t) {
        const int  x0   = xbase + t * TW;
        const bool intr = (x0 > 0) & (x0 < W - TW) & (y0 > 0) & (y0 < H - TH);
        __syncthreads();                    // sIP[buf] ready; sAB free
        if (t < NT - 1) issue(x0 + TW);     // prefetch next tile under S2 VALU
        if (intr) stage2<true >(sIP[buf], sAB, x0, y0, tid);
        else      stage2<false>(sIP[buf], sAB, x0, y0, tid);
        __syncthreads();                    // sAB ready
        if (t < NT - 1) {
            const int  x0n   = x0 + TW;
            const bool intrn = (x0n > 0) & (x0n < W - TW) & (y0 > 0) & (y0 < H - TH);
            commit(sIP[buf ^ 1], x0n, intrn);   // vmcnt + ds_write, off crit path
        }
        if (intr) stage3<true >(sAB, Ib, Ob, x0, y0, tid);
        else      stage3<false>(sAB, Ib, Ob, x0, y0, tid);
        buf ^= 1;
    }
}

extern "C" void kernel_launch(void* const* d_in, const int* in_sizes, int n_in,
                              void* d_out, int out_size, void* d_ws, size_t ws_size,
                              hipStream_t stream) {
    const float* I = (const float*)d_in[0];   // input
    const float* P = (const float*)d_in[1];   // guide
    float*       O = (float*)d_out;
    const int images = in_sizes[0] / (W * H); // B*C = 128
    dim3 grid(W / (NT * TW), H / TH, images); // (2, 32, 128)
    guide_filter_kernel<<<grid, dim3(256), 0, stream>>>(I, P, O);
}